// Round 3
// baseline (291.703 us; speedup 1.0000x reference)
//
#include <hip/hip_runtime.h>
#include <hip/hip_bf16.h>
#include <math.h>

#define BATCH   2
#define SEQ     2048
#define DMODEL  1024
#define NHEAD   16
#define DK      64
#define MTOK    (BATCH*SEQ)     // 4096
#define QKVN    (3*DMODEL)      // 3072
#define BH      (BATCH*NHEAD)   // 32

typedef __attribute__((ext_vector_type(8))) __bf16 bf16x8;
typedef __attribute__((ext_vector_type(4))) float  f32x4;

#define GL16(gp, lp) __builtin_amdgcn_global_load_lds( \
    (const __attribute__((address_space(1))) unsigned int*)(gp), \
    (__attribute__((address_space(3))) unsigned int*)(lp), 16, 0, 0)

// ---------------- fp32 -> bf16 convert --------------------------------------
__global__ __launch_bounds__(256) void cvt_bf16(const float* __restrict__ in,
                                                __hip_bfloat16* __restrict__ out, int n) {
    int i = (blockIdx.x * 256 + threadIdx.x) * 4;
    if (i >= n) return;
    float4 v = *(const float4*)(in + i);
    __hip_bfloat162 a, b;
    a.x = __float2bfloat16(v.x); a.y = __float2bfloat16(v.y);
    b.x = __float2bfloat16(v.z); b.y = __float2bfloat16(v.w);
    *(__hip_bfloat162*)(out + i)     = a;
    *(__hip_bfloat162*)(out + i + 2) = b;
}

// ---------------- bf16 MFMA GEMM (NT): C[M,N] = A[M,K] * B[N,K]^T ----------
#define GBM 128
#define GBN 128
#define GBK 32

template<int OUT_BF16>
__global__ __launch_bounds__(256) void gemm_bf16_nt(const __hip_bfloat16* __restrict__ A,
                                                    const __hip_bfloat16* __restrict__ B,
                                                    void* __restrict__ Cv,
                                                    int M, int N, int K) {
    __shared__ __align__(16) __hip_bfloat16 As[GBM][GBK];
    __shared__ __align__(16) __hip_bfloat16 Bs[GBN][GBK];
    const int tid  = threadIdx.x;
    const int wid  = tid >> 6;
    const int lane = tid & 63;
    const int fr   = lane & 15;
    const int fq   = lane >> 4;
    const int wm   = (wid >> 1) * 64;
    const int wn   = (wid & 1) * 64;
    const int m0   = blockIdx.y * GBM;
    const int n0   = blockIdx.x * GBN;

    f32x4 acc[4][4];
#pragma unroll
    for (int m = 0; m < 4; m++)
#pragma unroll
        for (int n = 0; n < 4; n++) acc[m][n] = (f32x4)0.f;

    const __hip_bfloat16* a0 = A + (size_t)(m0 + (tid >> 2)) * K + (tid & 3) * 8;
    const __hip_bfloat16* a1 = a0 + (size_t)64 * K;
    const __hip_bfloat16* b0 = B + (size_t)(n0 + (tid >> 2)) * K + (tid & 3) * 8;
    const __hip_bfloat16* b1 = b0 + (size_t)64 * K;
    __hip_bfloat16* asd0 = &As[0][0] + tid * 8;
    __hip_bfloat16* asd1 = asd0 + 2048;
    __hip_bfloat16* bsd0 = &Bs[0][0] + tid * 8;
    __hip_bfloat16* bsd1 = bsd0 + 2048;

    const __hip_bfloat16* ArP = &As[wm + fr][0] + fq * 8;
    const __hip_bfloat16* BrP = &Bs[wn + fr][0] + fq * 8;

    for (int k0 = 0; k0 < K; k0 += GBK) {
        GL16(a0 + k0, asd0);
        GL16(a1 + k0, asd1);
        GL16(b0 + k0, bsd0);
        GL16(b1 + k0, bsd1);
        __syncthreads();

        bf16x8 af[4], bfv[4];
#pragma unroll
        for (int m = 0; m < 4; m++) af[m]  = *(const bf16x8*)(ArP + m * 512);
#pragma unroll
        for (int n = 0; n < 4; n++) bfv[n] = *(const bf16x8*)(BrP + n * 512);
#pragma unroll
        for (int m = 0; m < 4; m++)
#pragma unroll
            for (int n = 0; n < 4; n++)
                acc[m][n] = __builtin_amdgcn_mfma_f32_16x16x32_bf16(af[m], bfv[n], acc[m][n], 0, 0, 0);
        __syncthreads();
    }

#pragma unroll
    for (int m = 0; m < 4; m++)
#pragma unroll
        for (int n = 0; n < 4; n++)
#pragma unroll
            for (int r = 0; r < 4; r++) {
                size_t row = m0 + wm + m * 16 + fq * 4 + r;
                size_t col = n0 + wn + n * 16 + fr;
                if (OUT_BF16)
                    ((__hip_bfloat16*)Cv)[row * N + col] = __float2bfloat16(acc[m][n][r]);
                else
                    ((float*)Cv)[row * N + col] = acc[m][n][r];
            }
}

// ---------------- RoPE + head-major repack of q,k ---------------------------
__global__ __launch_bounds__(256) void rope_qk(const __hip_bfloat16* __restrict__ qkvb,
                                               __hip_bfloat16* __restrict__ qh,
                                               __hip_bfloat16* __restrict__ kh) {
    int idx  = blockIdx.x * 256 + threadIdx.x;
    int row  = idx >> 10;
    int p    = idx & 1023;
    int half = p >> 9;
    int pp   = p & 511;
    int hh   = pp >> 5;
    int j    = pp & 31;
    int b    = row >> 11, s = row & (SEQ - 1);
    const __hip_bfloat16* src = qkvb + (size_t)row * QKVN + half * DMODEL + hh * DK + 2 * j;
    __hip_bfloat162 xv = *(const __hip_bfloat162*)src;
    float x1 = __bfloat162float(xv.x);
    float x2 = __bfloat162float(xv.y);
    float inv = exp2f(-(float)j * 0.41524101186092030f);
    float ang = (float)s * inv;
    float sn, cs;
    sincosf(ang, &sn, &cs);
    __hip_bfloat162 o;
    o.x = __float2bfloat16(x1 * cs - x2 * sn);
    o.y = __float2bfloat16(x1 * sn + x2 * cs);
    __hip_bfloat16* dst = (half ? kh : qh) + ((size_t)(b * NHEAD + hh) * SEQ + s) * DK + 2 * j;
    *(__hip_bfloat162*)dst = o;
}

// ---------------- V transpose (LDS-tiled): vt[bh][d][s] ---------------------
__global__ __launch_bounds__(256) void v_trans(const __hip_bfloat16* __restrict__ qkvb,
                                               __hip_bfloat16* __restrict__ vt) {
    __shared__ __hip_bfloat16 Ts[64][72];   // pad 64->72 (stride 144B, 16B-aligned)
    const int t  = threadIdx.x;
    const int s0 = blockIdx.x * 64;
    const int bh = blockIdx.y;
    const int b  = bh >> 4, h = bh & 15;
    const int sl = t >> 3;          // 0..31
    const int dc = (t & 7) * 8;     // 0,8,..56
#pragma unroll
    for (int i = 0; i < 2; i++) {
        int s = sl + i * 32;
        bf16x8 v = *(const bf16x8*)&qkvb[(size_t)(b * SEQ + s0 + s) * QKVN + 2 * DMODEL + h * DK + dc];
        *(bf16x8*)&Ts[s][dc] = v;
    }
    __syncthreads();
    const int dl = t >> 3;          // 0..31
    const int sc = (t & 7) * 8;
#pragma unroll
    for (int i = 0; i < 2; i++) {
        int d = dl + i * 32;
        bf16x8 o;
#pragma unroll
        for (int j = 0; j < 8; j++) o[j] = *(const __bf16*)&Ts[sc + j][d];
        *(bf16x8*)&vt[(size_t)bh * DK * SEQ + (size_t)d * SEQ + s0 + sc] = o;
    }
}

// ---------------- MFMA flash attention (causal) -----------------------------
// Block = (q-tile of 64, bh). 4 waves x 16 q-rows each, fully independent.
// Grid 1024, heavy tiles first. K loads then V loads issued before QK^T so V
// latency hides under softmax (in-order vmcnt: QK waits only on K).
__global__ __launch_bounds__(256) void attn_mfma(const __hip_bfloat16* __restrict__ qh,
                                                 const __hip_bfloat16* __restrict__ kh,
                                                 const __hip_bfloat16* __restrict__ vt,
                                                 __hip_bfloat16* __restrict__ mergedb) {
    __shared__ __align__(16) __hip_bfloat16 Ps[4][1024];   // 2 KB per wave
    const int tid = threadIdx.x, wid = tid >> 6, lane = tid & 63;
    const int fr = lane & 15, fq = lane >> 4;
    const int bid = blockIdx.x;                 // 1024 blocks
    const int qt  = 31 - (bid >> 5);            // heavy first
    const int bh  = bid & 31;
    const int b   = bh >> 4, h = bh & 15;

    const size_t hoff = (size_t)bh * SEQ * DK;
    const __hip_bfloat16* Qb = qh + hoff;
    const __hip_bfloat16* Kb = kh + hoff;
    const __hip_bfloat16* Vb = vt + hoff;       // [64][SEQ]

    const int q0 = qt * 64 + wid * 16;          // wave's first global q-row

    bf16x8 qf[2];
#pragma unroll
    for (int c = 0; c < 2; c++)
        qf[c] = *(const bf16x8*)&Qb[(size_t)(q0 + fr) * DK + c * 32 + fq * 8];

    f32x4 o[4];
#pragma unroll
    for (int n = 0; n < 4; n++) o[n] = (f32x4)0.f;
    float mrun[4], lrun[4];
#pragma unroll
    for (int i = 0; i < 4; i++) { mrun[i] = -INFINITY; lrun[i] = 0.f; }

    char* Pw = (char*)&Ps[wid][0];

    for (int kt = 0; kt <= qt; kt++) {
        const int key0 = kt * 64;
        // ---- issue K loads first, then V loads (V stays in flight to PV)
        bf16x8 kf[4][2];
#pragma unroll
        for (int n = 0; n < 4; n++)
#pragma unroll
            for (int c = 0; c < 2; c++)
                kf[n][c] = *(const bf16x8*)&Kb[(size_t)(key0 + n * 16 + fr) * DK + c * 32 + fq * 8];
        bf16x8 vf[4][2];
#pragma unroll
        for (int n = 0; n < 4; n++)
#pragma unroll
            for (int c = 0; c < 2; c++)
                vf[n][c] = *(const bf16x8*)&Vb[(size_t)(n * 16 + fr) * SEQ + key0 + c * 32 + fq * 8];

        // ---- S = Q K^T
        f32x4 s_acc[4];
#pragma unroll
        for (int n = 0; n < 4; n++) s_acc[n] = (f32x4)0.f;
#pragma unroll
        for (int n = 0; n < 4; n++) {
            s_acc[n] = __builtin_amdgcn_mfma_f32_16x16x32_bf16(qf[0], kf[n][0], s_acc[n], 0, 0, 0);
            s_acc[n] = __builtin_amdgcn_mfma_f32_16x16x32_bf16(qf[1], kf[n][1], s_acc[n], 0, 0, 0);
        }
#pragma unroll
        for (int n = 0; n < 4; n++)
#pragma unroll
            for (int r = 0; r < 4; r++) s_acc[n][r] *= 0.125f;
        if (kt == qt) {
#pragma unroll
            for (int n = 0; n < 4; n++)
#pragma unroll
                for (int r = 0; r < 4; r++) {
                    int qrow = q0 + fq * 4 + r;
                    int key  = key0 + n * 16 + fr;
                    if (key > qrow) s_acc[n][r] = -INFINITY;
                }
        }

        // ---- online softmax (rows fq*4+r, reduce over 16-lane group)
        float corr[4];
#pragma unroll
        for (int r = 0; r < 4; r++) {
            float mx = fmaxf(fmaxf(s_acc[0][r], s_acc[1][r]),
                             fmaxf(s_acc[2][r], s_acc[3][r]));
            mx = fmaxf(mx, __shfl_xor(mx, 1));
            mx = fmaxf(mx, __shfl_xor(mx, 2));
            mx = fmaxf(mx, __shfl_xor(mx, 4));
            mx = fmaxf(mx, __shfl_xor(mx, 8));
            float mnew = fmaxf(mrun[r], mx);
            corr[r] = __expf(mrun[r] - mnew);
            mrun[r] = mnew;
            float rs = 0.f;
#pragma unroll
            for (int n = 0; n < 4; n++) {
                float pv = __expf(s_acc[n][r] - mnew);
                s_acc[n][r] = pv;
                rs += pv;
            }
            rs += __shfl_xor(rs, 1);
            rs += __shfl_xor(rs, 2);
            rs += __shfl_xor(rs, 4);
            rs += __shfl_xor(rs, 8);
            lrun[r] = lrun[r] * corr[r] + rs;
#pragma unroll
            for (int n = 0; n < 4; n++) o[n][r] *= corr[r];
        }

        // ---- P -> LDS (bf16, XOR-swizzled rows; row stride 128B)
#pragma unroll
        for (int r = 0; r < 4; r++) {
            int rl = fq * 4 + r;
            int sw = (rl & 7) << 4;
#pragma unroll
            for (int n = 0; n < 4; n++) {
                int key = n * 16 + fr;
                *(__hip_bfloat16*)(Pw + (((rl << 7) + (key << 1)) ^ sw)) =
                    __float2bfloat16(s_acc[n][r]);
            }
        }
        asm volatile("s_waitcnt lgkmcnt(0)" ::: "memory");
        __builtin_amdgcn_sched_barrier(0);

        // ---- PV (V frags already in flight/landed)
        bf16x8 pa[2];
#pragma unroll
        for (int c = 0; c < 2; c++)
            pa[c] = *(const bf16x8*)(Pw + (((fr << 7) + ((c * 32 + fq * 8) << 1)) ^ ((fr & 7) << 4)));
#pragma unroll
        for (int n = 0; n < 4; n++) {
            o[n] = __builtin_amdgcn_mfma_f32_16x16x32_bf16(pa[0], vf[n][0], o[n], 0, 0, 0);
            o[n] = __builtin_amdgcn_mfma_f32_16x16x32_bf16(pa[1], vf[n][1], o[n], 0, 0, 0);
        }
    }

    // ---- normalize + store merged bf16
#pragma unroll
    for (int r = 0; r < 4; r++) {
        float invl = 1.0f / lrun[r];
        int qrow = q0 + fq * 4 + r;
#pragma unroll
        for (int n = 0; n < 4; n++) {
            int col = h * DK + n * 16 + fr;
            mergedb[(size_t)(b * SEQ + qrow) * DMODEL + col] =
                __float2bfloat16(o[n][r] * invl);
        }
    }
}

// ---------------- launch ----------------------------------------------------
extern "C" void kernel_launch(void* const* d_in, const int* in_sizes, int n_in,
                              void* d_out, int out_size, void* d_ws, size_t ws_size,
                              hipStream_t stream) {
    const float* x    = (const float*)d_in[0];
    const float* Wqkv = (const float*)d_in[1];
    const float* Wout = (const float*)d_in[2];
    float* out = (float*)d_out;

    char* w = (char*)d_ws;
    __hip_bfloat16* qkvb   = (__hip_bfloat16*)(w);                       // 24 MB
    __hip_bfloat16* qh     = (__hip_bfloat16*)(w + (24u << 20));         //  8 MB
    __hip_bfloat16* kh     = (__hip_bfloat16*)(w + (32u << 20));         //  8 MB
    __hip_bfloat16* vt     = (__hip_bfloat16*)(w + (40u << 20));         //  8 MB
    __hip_bfloat16* xb     = (__hip_bfloat16*)(w + (48u << 20));         //  8 MB
    __hip_bfloat16* merged = (__hip_bfloat16*)(w + (48u << 20));         //  8 MB (after xb dead)
    __hip_bfloat16* wqkvb  = (__hip_bfloat16*)(w + (56u << 20));         //  6 MB
    __hip_bfloat16* woutb  = (__hip_bfloat16*)(w + (62u << 20));         //  2 MB

    cvt_bf16<<<MTOK * DMODEL / 1024, 256, 0, stream>>>(x, xb, MTOK * DMODEL);
    cvt_bf16<<<QKVN * DMODEL / 1024, 256, 0, stream>>>(Wqkv, wqkvb, QKVN * DMODEL);
    cvt_bf16<<<DMODEL * DMODEL / 1024, 256, 0, stream>>>(Wout, woutb, DMODEL * DMODEL);

    dim3 g1(QKVN / GBN, MTOK / GBM);
    gemm_bf16_nt<1><<<g1, 256, 0, stream>>>(xb, wqkvb, qkvb, MTOK, QKVN, DMODEL);

    rope_qk<<<MTOK * 1024 / 256, 256, 0, stream>>>(qkvb, qh, kh);
    v_trans<<<dim3(SEQ / 64, BH), 256, 0, stream>>>(qkvb, vt);

    attn_mfma<<<1024, 256, 0, stream>>>(qh, kh, vt, merged);

    dim3 g3(DMODEL / GBN, MTOK / GBM);
    gemm_bf16_nt<0><<<g3, 256, 0, stream>>>(merged, woutb, out, MTOK, DMODEL, DMODEL);
}

// Round 4
// 258.530 us; speedup vs baseline: 1.1283x; 1.1283x over previous
//
#include <hip/hip_runtime.h>
#include <hip/hip_bf16.h>
#include <math.h>

#define BATCH   2
#define SEQ     2048
#define DMODEL  1024
#define NHEAD   16
#define DK      64
#define MTOK    (BATCH*SEQ)     // 4096
#define QKVN    (3*DMODEL)      // 3072
#define BH      (BATCH*NHEAD)   // 32

typedef __attribute__((ext_vector_type(8))) __bf16 bf16x8;
typedef __attribute__((ext_vector_type(4))) float  f32x4;

#define GL16(gp, lp) __builtin_amdgcn_global_load_lds( \
    (const __attribute__((address_space(1))) unsigned int*)(gp), \
    (__attribute__((address_space(3))) unsigned int*)(lp), 16, 0, 0)

// ---------------- fp32 -> bf16 convert --------------------------------------
__global__ __launch_bounds__(256) void cvt_bf16(const float* __restrict__ in,
                                                __hip_bfloat16* __restrict__ out, int n) {
    int i = (blockIdx.x * 256 + threadIdx.x) * 4;
    if (i >= n) return;
    float4 v = *(const float4*)(in + i);
    __hip_bfloat162 a, b;
    a.x = __float2bfloat16(v.x); a.y = __float2bfloat16(v.y);
    b.x = __float2bfloat16(v.z); b.y = __float2bfloat16(v.w);
    *(__hip_bfloat162*)(out + i)     = a;
    *(__hip_bfloat162*)(out + i + 2) = b;
}

// ---------------- bf16 MFMA GEMM (NT): C[M,N] = A[M,K] * B[N,K]^T ----------
#define GBM 128
#define GBN 128
#define GBK 32

template<int OUT_BF16>
__global__ __launch_bounds__(256) void gemm_bf16_nt(const __hip_bfloat16* __restrict__ A,
                                                    const __hip_bfloat16* __restrict__ B,
                                                    void* __restrict__ Cv,
                                                    int M, int N, int K) {
    __shared__ __align__(16) __hip_bfloat16 As[GBM][GBK];
    __shared__ __align__(16) __hip_bfloat16 Bs[GBN][GBK];
    const int tid  = threadIdx.x;
    const int wid  = tid >> 6;
    const int lane = tid & 63;
    const int fr   = lane & 15;
    const int fq   = lane >> 4;
    const int wm   = (wid >> 1) * 64;
    const int wn   = (wid & 1) * 64;
    const int m0   = blockIdx.y * GBM;
    const int n0   = blockIdx.x * GBN;

    f32x4 acc[4][4];
#pragma unroll
    for (int m = 0; m < 4; m++)
#pragma unroll
        for (int n = 0; n < 4; n++) acc[m][n] = (f32x4)0.f;

    const __hip_bfloat16* a0 = A + (size_t)(m0 + (tid >> 2)) * K + (tid & 3) * 8;
    const __hip_bfloat16* a1 = a0 + (size_t)64 * K;
    const __hip_bfloat16* b0 = B + (size_t)(n0 + (tid >> 2)) * K + (tid & 3) * 8;
    const __hip_bfloat16* b1 = b0 + (size_t)64 * K;
    __hip_bfloat16* asd0 = &As[0][0] + tid * 8;
    __hip_bfloat16* asd1 = asd0 + 2048;
    __hip_bfloat16* bsd0 = &Bs[0][0] + tid * 8;
    __hip_bfloat16* bsd1 = bsd0 + 2048;

    const __hip_bfloat16* ArP = &As[wm + fr][0] + fq * 8;
    const __hip_bfloat16* BrP = &Bs[wn + fr][0] + fq * 8;

    for (int k0 = 0; k0 < K; k0 += GBK) {
        GL16(a0 + k0, asd0);
        GL16(a1 + k0, asd1);
        GL16(b0 + k0, bsd0);
        GL16(b1 + k0, bsd1);
        __syncthreads();

        bf16x8 af[4], bfv[4];
#pragma unroll
        for (int m = 0; m < 4; m++) af[m]  = *(const bf16x8*)(ArP + m * 512);
#pragma unroll
        for (int n = 0; n < 4; n++) bfv[n] = *(const bf16x8*)(BrP + n * 512);
#pragma unroll
        for (int m = 0; m < 4; m++)
#pragma unroll
            for (int n = 0; n < 4; n++)
                acc[m][n] = __builtin_amdgcn_mfma_f32_16x16x32_bf16(af[m], bfv[n], acc[m][n], 0, 0, 0);
        __syncthreads();
    }

#pragma unroll
    for (int m = 0; m < 4; m++)
#pragma unroll
        for (int n = 0; n < 4; n++)
#pragma unroll
            for (int r = 0; r < 4; r++) {
                size_t row = m0 + wm + m * 16 + fq * 4 + r;
                size_t col = n0 + wn + n * 16 + fr;
                if (OUT_BF16)
                    ((__hip_bfloat16*)Cv)[row * N + col] = __float2bfloat16(acc[m][n][r]);
                else
                    ((float*)Cv)[row * N + col] = acc[m][n][r];
            }
}

// ---------------- RoPE + head-major repack of q,k ---------------------------
// Q is pre-scaled by 1/sqrt(dk) = 0.125 (exact power of 2).
__global__ __launch_bounds__(256) void rope_qk(const __hip_bfloat16* __restrict__ qkvb,
                                               __hip_bfloat16* __restrict__ qh,
                                               __hip_bfloat16* __restrict__ kh) {
    int idx  = blockIdx.x * 256 + threadIdx.x;
    int row  = idx >> 10;
    int p    = idx & 1023;
    int half = p >> 9;
    int pp   = p & 511;
    int hh   = pp >> 5;
    int j    = pp & 31;
    int b    = row >> 11, s = row & (SEQ - 1);
    const __hip_bfloat16* src = qkvb + (size_t)row * QKVN + half * DMODEL + hh * DK + 2 * j;
    __hip_bfloat162 xv = *(const __hip_bfloat162*)src;
    float x1 = __bfloat162float(xv.x);
    float x2 = __bfloat162float(xv.y);
    float inv = exp2f(-(float)j * 0.41524101186092030f);
    float ang = (float)s * inv;
    float sn, cs;
    sincosf(ang, &sn, &cs);
    float sc = half ? 1.0f : 0.125f;
    __hip_bfloat162 o;
    o.x = __float2bfloat16((x1 * cs - x2 * sn) * sc);
    o.y = __float2bfloat16((x1 * sn + x2 * cs) * sc);
    __hip_bfloat16* dst = (half ? kh : qh) + ((size_t)(b * NHEAD + hh) * SEQ + s) * DK + 2 * j;
    *(__hip_bfloat162*)dst = o;
}

// ---------------- V transpose (LDS-tiled): vt[bh][d][s] ---------------------
__global__ __launch_bounds__(256) void v_trans(const __hip_bfloat16* __restrict__ qkvb,
                                               __hip_bfloat16* __restrict__ vt) {
    __shared__ __hip_bfloat16 Ts[64][72];
    const int t  = threadIdx.x;
    const int s0 = blockIdx.x * 64;
    const int bh = blockIdx.y;
    const int b  = bh >> 4, h = bh & 15;
    const int sl = t >> 3;
    const int dc = (t & 7) * 8;
#pragma unroll
    for (int i = 0; i < 2; i++) {
        int s = sl + i * 32;
        bf16x8 v = *(const bf16x8*)&qkvb[(size_t)(b * SEQ + s0 + s) * QKVN + 2 * DMODEL + h * DK + dc];
        *(bf16x8*)&Ts[s][dc] = v;
    }
    __syncthreads();
    const int dl = t >> 3;
    const int sc = (t & 7) * 8;
#pragma unroll
    for (int i = 0; i < 2; i++) {
        int d = dl + i * 32;
        bf16x8 o;
#pragma unroll
        for (int j = 0; j < 8; j++) o[j] = *(const __bf16*)&Ts[sc + j][d];
        *(bf16x8*)&vt[(size_t)bh * DK * SEQ + (size_t)d * SEQ + s0 + sc] = o;
    }
}

// ---------------- MFMA flash attention (causal) -----------------------------
// Block = (q-tile of 128, bh), 4 waves x 32 q-rows. K/V tiles (64 keys) staged
// in LDS once per block via global_load_lds, double-buffered: stage(kt+1) is
// issued BEFORE compute(kt); the single __syncthreads per tile drains it after
// compute has hidden the latency. LDS reads XOR-swizzled (linear dest +
// inverse-swizzled global source, rule both-sides-or-neither).
__global__ __launch_bounds__(256) void attn_mfma(const __hip_bfloat16* __restrict__ qh,
                                                 const __hip_bfloat16* __restrict__ kh,
                                                 const __hip_bfloat16* __restrict__ vt,
                                                 __hip_bfloat16* __restrict__ mergedb) {
    __shared__ __align__(16) __hip_bfloat16 Kbuf[2][4096];  // 8 KB each: [64 keys][64 d]
    __shared__ __align__(16) __hip_bfloat16 Vbuf[2][4096];  // 8 KB each: [64 d][64 keys]
    __shared__ __align__(16) __hip_bfloat16 Ps[4][2048];    // 4 KB per wave
    const int tid = threadIdx.x, wid = tid >> 6, lane = tid & 63;
    const int fr = lane & 15, fq = lane >> 4;
    const int bid = blockIdx.x;                 // 512 blocks
    const int qt  = 15 - (bid >> 5);            // heavy tiles first
    const int bh  = bid & 31;
    const int b   = bh >> 4, h = bh & 15;

    const size_t hoff = (size_t)bh * SEQ * DK;
    const __hip_bfloat16* Qb = qh + hoff;
    const char* Kc = (const char*)(kh + hoff);  // [2048 keys][64 d] rows of 128B
    const char* Vc = (const char*)(vt + hoff);  // [64 d][2048 keys] rows of 4096B

    const int q0  = qt * 128 + wid * 32;        // wave's first q-row
    const int nkt = 2 * qt + 2;

    // staging: thread owns LDS 16B chunks at L0, L1 of each 8KB buffer; global
    // source pre-swizzled so that swizzled READS return linear data.
    const int L0 = tid * 16, L1 = L0 + 4096;
    const int r0 = L0 >> 7,  r1 = L1 >> 7;
    const int ks0 = L0 ^ ((r0 & 7) << 4);
    const int ks1 = L1 ^ ((r1 & 7) << 4);
    const int vc0 = (L0 & 127) ^ ((r0 & 7) << 4);
    const int vc1 = (L1 & 127) ^ ((r1 & 7) << 4);

    auto stage = [&](int kts) {
        const char* Kt = Kc + (size_t)kts * 8192;   // key0 * 128B
        const char* Vt = Vc + (size_t)kts * 128;    // key0 * 2B
        char* kd = (char*)&Kbuf[kts & 1][0];
        char* vd = (char*)&Vbuf[kts & 1][0];
        GL16(Kt + ks0, kd + L0);
        GL16(Kt + ks1, kd + L1);
        GL16(Vt + (size_t)r0 * 4096 + vc0, vd + L0);
        GL16(Vt + (size_t)r1 * 4096 + vc1, vd + L1);
    };

    bf16x8 qf[2][2];
#pragma unroll
    for (int m = 0; m < 2; m++)
#pragma unroll
        for (int c = 0; c < 2; c++)
            qf[m][c] = *(const bf16x8*)&Qb[(size_t)(q0 + m * 16 + fr) * DK + c * 32 + fq * 8];

    f32x4 o[2][4];
#pragma unroll
    for (int m = 0; m < 2; m++)
#pragma unroll
        for (int n = 0; n < 4; n++) o[m][n] = (f32x4)0.f;
    float mrun[8], lrun[8];
#pragma unroll
    for (int i = 0; i < 8; i++) { mrun[i] = -INFINITY; lrun[i] = 0.f; }

    char* Pw = (char*)&Ps[wid][0];
    const int swf = (fr & 7) << 4;

    stage(0);
    __syncthreads();

    for (int kt = 0; kt < nkt; kt++) {
        if (kt + 1 < nkt) stage(kt + 1);        // in flight during compute
        const int key0 = kt * 64;
        const bool active = (key0 <= q0 + 31);  // wave-uniform
        if (active) {
            const char* Kl = (const char*)&Kbuf[kt & 1][0];
            const char* Vl = (const char*)&Vbuf[kt & 1][0];
            bf16x8 kf[4][2];
#pragma unroll
            for (int n = 0; n < 4; n++)
#pragma unroll
                for (int c = 0; c < 2; c++)
                    kf[n][c] = *(const bf16x8*)(Kl + ((((n * 16 + fr) << 7) + (c << 6) + (fq << 4)) ^ swf));

            f32x4 s_acc[2][4];
#pragma unroll
            for (int m = 0; m < 2; m++)
#pragma unroll
                for (int n = 0; n < 4; n++) s_acc[m][n] = (f32x4)0.f;
            __builtin_amdgcn_s_setprio(1);
#pragma unroll
            for (int n = 0; n < 4; n++)
#pragma unroll
                for (int m = 0; m < 2; m++) {
                    s_acc[m][n] = __builtin_amdgcn_mfma_f32_16x16x32_bf16(qf[m][0], kf[n][0], s_acc[m][n], 0, 0, 0);
                    s_acc[m][n] = __builtin_amdgcn_mfma_f32_16x16x32_bf16(qf[m][1], kf[n][1], s_acc[m][n], 0, 0, 0);
                }
            __builtin_amdgcn_s_setprio(0);

            if (key0 + 63 > q0) {               // diagonal tile for this wave
#pragma unroll
                for (int m = 0; m < 2; m++)
#pragma unroll
                    for (int n = 0; n < 4; n++)
#pragma unroll
                        for (int r = 0; r < 4; r++) {
                            int qrow = q0 + m * 16 + fq * 4 + r;
                            int key  = key0 + n * 16 + fr;
                            if (key > qrow) s_acc[m][n][r] = -INFINITY;
                        }
            }

            // online softmax per row (16-lane-group reductions)
#pragma unroll
            for (int m = 0; m < 2; m++)
#pragma unroll
                for (int r = 0; r < 4; r++) {
                    float mx = fmaxf(fmaxf(s_acc[m][0][r], s_acc[m][1][r]),
                                     fmaxf(s_acc[m][2][r], s_acc[m][3][r]));
                    mx = fmaxf(mx, __shfl_xor(mx, 1));
                    mx = fmaxf(mx, __shfl_xor(mx, 2));
                    mx = fmaxf(mx, __shfl_xor(mx, 4));
                    mx = fmaxf(mx, __shfl_xor(mx, 8));
                    const int ri = m * 4 + r;
                    float mnew = fmaxf(mrun[ri], mx);
                    float corr = __expf(mrun[ri] - mnew);
                    mrun[ri] = mnew;
                    float rs = 0.f;
#pragma unroll
                    for (int n = 0; n < 4; n++) {
                        float pv = __expf(s_acc[m][n][r] - mnew);
                        s_acc[m][n][r] = pv;
                        rs += pv;
                    }
                    rs += __shfl_xor(rs, 1);
                    rs += __shfl_xor(rs, 2);
                    rs += __shfl_xor(rs, 4);
                    rs += __shfl_xor(rs, 8);
                    lrun[ri] = lrun[ri] * corr + rs;
#pragma unroll
                    for (int n = 0; n < 4; n++) o[m][n][r] *= corr;
                }

            // V frags (in flight during P-store)
            bf16x8 vf[4][2];
#pragma unroll
            for (int n = 0; n < 4; n++)
#pragma unroll
                for (int c = 0; c < 2; c++)
                    vf[n][c] = *(const bf16x8*)(Vl + ((((n * 16 + fr) << 7) + (c << 6) + (fq << 4)) ^ swf));

            // P -> per-wave LDS slab (XOR-swizzled rows, stride 128B)
#pragma unroll
            for (int m = 0; m < 2; m++)
#pragma unroll
                for (int r = 0; r < 4; r++) {
                    int rl = m * 16 + fq * 4 + r;
                    int sw = (rl & 7) << 4;
#pragma unroll
                    for (int n = 0; n < 4; n++) {
                        int key = n * 16 + fr;
                        *(__hip_bfloat16*)(Pw + (((rl << 7) + (key << 1)) ^ sw)) =
                            __float2bfloat16(s_acc[m][n][r]);
                    }
                }
            asm volatile("s_waitcnt lgkmcnt(0)" ::: "memory");
            __builtin_amdgcn_sched_barrier(0);

            bf16x8 pa[2][2];
#pragma unroll
            for (int m = 0; m < 2; m++)
#pragma unroll
                for (int c = 0; c < 2; c++) {
                    int rl = m * 16 + fr;
                    pa[m][c] = *(const bf16x8*)(Pw + (((rl << 7) + ((c * 32 + fq * 8) << 1)) ^ ((rl & 7) << 4)));
                }
            __builtin_amdgcn_s_setprio(1);
#pragma unroll
            for (int n = 0; n < 4; n++)
#pragma unroll
                for (int m = 0; m < 2; m++) {
                    o[m][n] = __builtin_amdgcn_mfma_f32_16x16x32_bf16(pa[m][0], vf[n][0], o[m][n], 0, 0, 0);
                    o[m][n] = __builtin_amdgcn_mfma_f32_16x16x32_bf16(pa[m][1], vf[n][1], o[m][n], 0, 0, 0);
                }
            __builtin_amdgcn_s_setprio(0);
        }
        __syncthreads();   // drains stage(kt+1) vmcnt + protects buf reuse
    }

    // normalize + store merged bf16
#pragma unroll
    for (int m = 0; m < 2; m++)
#pragma unroll
        for (int r = 0; r < 4; r++) {
            float invl = 1.0f / lrun[m * 4 + r];
            int qrow = q0 + m * 16 + fq * 4 + r;
#pragma unroll
            for (int n = 0; n < 4; n++) {
                int col = h * DK + n * 16 + fr;
                mergedb[(size_t)(b * SEQ + qrow) * DMODEL + col] =
                    __float2bfloat16(o[m][n][r] * invl);
            }
        }
}

// ---------------- launch ----------------------------------------------------
extern "C" void kernel_launch(void* const* d_in, const int* in_sizes, int n_in,
                              void* d_out, int out_size, void* d_ws, size_t ws_size,
                              hipStream_t stream) {
    const float* x    = (const float*)d_in[0];
    const float* Wqkv = (const float*)d_in[1];
    const float* Wout = (const float*)d_in[2];
    float* out = (float*)d_out;

    char* w = (char*)d_ws;
    __hip_bfloat16* qkvb   = (__hip_bfloat16*)(w);                       // 24 MB
    __hip_bfloat16* qh     = (__hip_bfloat16*)(w + (24u << 20));         //  8 MB
    __hip_bfloat16* kh     = (__hip_bfloat16*)(w + (32u << 20));         //  8 MB
    __hip_bfloat16* vt     = (__hip_bfloat16*)(w + (40u << 20));         //  8 MB
    __hip_bfloat16* xb     = (__hip_bfloat16*)(w + (48u << 20));         //  8 MB
    __hip_bfloat16* merged = (__hip_bfloat16*)(w + (48u << 20));         //  8 MB (after xb dead)
    __hip_bfloat16* wqkvb  = (__hip_bfloat16*)(w + (56u << 20));         //  6 MB
    __hip_bfloat16* woutb  = (__hip_bfloat16*)(w + (62u << 20));         //  2 MB

    cvt_bf16<<<MTOK * DMODEL / 1024, 256, 0, stream>>>(x, xb, MTOK * DMODEL);
    cvt_bf16<<<QKVN * DMODEL / 1024, 256, 0, stream>>>(Wqkv, wqkvb, QKVN * DMODEL);
    cvt_bf16<<<DMODEL * DMODEL / 1024, 256, 0, stream>>>(Wout, woutb, DMODEL * DMODEL);

    dim3 g1(QKVN / GBN, MTOK / GBM);
    gemm_bf16_nt<1><<<g1, 256, 0, stream>>>(xb, wqkvb, qkvb, MTOK, QKVN, DMODEL);

    rope_qk<<<MTOK * 1024 / 256, 256, 0, stream>>>(qkvb, qh, kh);
    v_trans<<<dim3(SEQ / 64, BH), 256, 0, stream>>>(qkvb, vt);

    attn_mfma<<<512, 256, 0, stream>>>(qh, kh, vt, merged);

    dim3 g3(DMODEL / GBN, MTOK / GBM);
    gemm_bf16_nt<0><<<g3, 256, 0, stream>>>(merged, woutb, out, MTOK, DMODEL, DMODEL);
}

// Round 6
// 233.263 us; speedup vs baseline: 1.2505x; 1.1083x over previous
//
#include <hip/hip_runtime.h>
#include <hip/hip_bf16.h>
#include <math.h>

#define BATCH   2
#define SEQ     2048
#define DMODEL  1024
#define NHEAD   16
#define DK      64
#define MTOK    (BATCH*SEQ)     // 4096
#define QKVN    (3*DMODEL)      // 3072
#define BH      (BATCH*NHEAD)   // 32

typedef __attribute__((ext_vector_type(8)))  __bf16 bf16x8;
typedef __attribute__((ext_vector_type(4)))  float  f32x4;
typedef __attribute__((ext_vector_type(16))) float  f32x16;

#define GL16(gp, lp) __builtin_amdgcn_global_load_lds( \
    (const __attribute__((address_space(1))) unsigned int*)(gp), \
    (__attribute__((address_space(3))) unsigned int*)(lp), 16, 0, 0)

// ---------------- fp32 -> bf16 convert --------------------------------------
__global__ __launch_bounds__(256) void cvt_bf16(const float* __restrict__ in,
                                                __hip_bfloat16* __restrict__ out, int n) {
    int i = (blockIdx.x * 256 + threadIdx.x) * 4;
    if (i >= n) return;
    float4 v = *(const float4*)(in + i);
    __hip_bfloat162 a, b;
    a.x = __float2bfloat16(v.x); a.y = __float2bfloat16(v.y);
    b.x = __float2bfloat16(v.z); b.y = __float2bfloat16(v.w);
    *(__hip_bfloat162*)(out + i)     = a;
    *(__hip_bfloat162*)(out + i + 2) = b;
}

// ---------------- bf16 MFMA GEMM (NT): C[M,N] = A[M,K] * B[N,K]^T ----------
#define GBM 128
#define GBN 128
#define GBK 32

template<int OUT_BF16>
__global__ __launch_bounds__(256) void gemm_bf16_nt(const __hip_bfloat16* __restrict__ A,
                                                    const __hip_bfloat16* __restrict__ B,
                                                    void* __restrict__ Cv,
                                                    int M, int N, int K) {
    __shared__ __align__(16) __hip_bfloat16 As[GBM][GBK];
    __shared__ __align__(16) __hip_bfloat16 Bs[GBN][GBK];
    const int tid  = threadIdx.x;
    const int wid  = tid >> 6;
    const int lane = tid & 63;
    const int fr   = lane & 15;
    const int fq   = lane >> 4;
    const int wm   = (wid >> 1) * 64;
    const int wn   = (wid & 1) * 64;
    const int m0   = blockIdx.y * GBM;
    const int n0   = blockIdx.x * GBN;

    f32x4 acc[4][4];
#pragma unroll
    for (int m = 0; m < 4; m++)
#pragma unroll
        for (int n = 0; n < 4; n++) acc[m][n] = (f32x4)0.f;

    const __hip_bfloat16* a0 = A + (size_t)(m0 + (tid >> 2)) * K + (tid & 3) * 8;
    const __hip_bfloat16* a1 = a0 + (size_t)64 * K;
    const __hip_bfloat16* b0 = B + (size_t)(n0 + (tid >> 2)) * K + (tid & 3) * 8;
    const __hip_bfloat16* b1 = b0 + (size_t)64 * K;
    __hip_bfloat16* asd0 = &As[0][0] + tid * 8;
    __hip_bfloat16* asd1 = asd0 + 2048;
    __hip_bfloat16* bsd0 = &Bs[0][0] + tid * 8;
    __hip_bfloat16* bsd1 = bsd0 + 2048;

    const __hip_bfloat16* ArP = &As[wm + fr][0] + fq * 8;
    const __hip_bfloat16* BrP = &Bs[wn + fr][0] + fq * 8;

    for (int k0 = 0; k0 < K; k0 += GBK) {
        GL16(a0 + k0, asd0);
        GL16(a1 + k0, asd1);
        GL16(b0 + k0, bsd0);
        GL16(b1 + k0, bsd1);
        __syncthreads();

        bf16x8 af[4], bfv[4];
#pragma unroll
        for (int m = 0; m < 4; m++) af[m]  = *(const bf16x8*)(ArP + m * 512);
#pragma unroll
        for (int n = 0; n < 4; n++) bfv[n] = *(const bf16x8*)(BrP + n * 512);
#pragma unroll
        for (int m = 0; m < 4; m++)
#pragma unroll
            for (int n = 0; n < 4; n++)
                acc[m][n] = __builtin_amdgcn_mfma_f32_16x16x32_bf16(af[m], bfv[n], acc[m][n], 0, 0, 0);
        __syncthreads();
    }

#pragma unroll
    for (int m = 0; m < 4; m++)
#pragma unroll
        for (int n = 0; n < 4; n++)
#pragma unroll
            for (int r = 0; r < 4; r++) {
                size_t row = m0 + wm + m * 16 + fq * 4 + r;
                size_t col = n0 + wn + n * 16 + fr;
                if (OUT_BF16)
                    ((__hip_bfloat16*)Cv)[row * N + col] = __float2bfloat16(acc[m][n][r]);
                else
                    ((float*)Cv)[row * N + col] = acc[m][n][r];
            }
}

// ---------------- RoPE + head-major repack of q,k ---------------------------
// Q pre-scaled by 1/sqrt(dk) = 0.125 (exact power of 2).
__global__ __launch_bounds__(256) void rope_qk(const __hip_bfloat16* __restrict__ qkvb,
                                               __hip_bfloat16* __restrict__ qh,
                                               __hip_bfloat16* __restrict__ kh) {
    int idx  = blockIdx.x * 256 + threadIdx.x;
    int row  = idx >> 10;
    int p    = idx & 1023;
    int half = p >> 9;
    int pp   = p & 511;
    int hh   = pp >> 5;
    int j    = pp & 31;
    int b    = row >> 11, s = row & (SEQ - 1);
    const __hip_bfloat16* src = qkvb + (size_t)row * QKVN + half * DMODEL + hh * DK + 2 * j;
    __hip_bfloat162 xv = *(const __hip_bfloat162*)src;
    float x1 = __bfloat162float(xv.x);
    float x2 = __bfloat162float(xv.y);
    float inv = exp2f(-(float)j * 0.41524101186092030f);
    float ang = (float)s * inv;
    float sn, cs;
    sincosf(ang, &sn, &cs);
    float sc = half ? 1.0f : 0.125f;
    __hip_bfloat162 o;
    o.x = __float2bfloat16((x1 * cs - x2 * sn) * sc);
    o.y = __float2bfloat16((x1 * sn + x2 * cs) * sc);
    __hip_bfloat16* dst = (half ? kh : qh) + ((size_t)(b * NHEAD + hh) * SEQ + s) * DK + 2 * j;
    *(__hip_bfloat162*)dst = o;
}

// ---------------- V transpose (LDS-tiled): vt[bh][d][s] ---------------------
__global__ __launch_bounds__(256) void v_trans(const __hip_bfloat16* __restrict__ qkvb,
                                               __hip_bfloat16* __restrict__ vt) {
    __shared__ __hip_bfloat16 Ts[64][72];
    const int t  = threadIdx.x;
    const int s0 = blockIdx.x * 64;
    const int bh = blockIdx.y;
    const int b  = bh >> 4, h = bh & 15;
    const int sl = t >> 3;
    const int dc = (t & 7) * 8;
#pragma unroll
    for (int i = 0; i < 2; i++) {
        int s = sl + i * 32;
        bf16x8 v = *(const bf16x8*)&qkvb[(size_t)(b * SEQ + s0 + s) * QKVN + 2 * DMODEL + h * DK + dc];
        *(bf16x8*)&Ts[s][dc] = v;
    }
    __syncthreads();
    const int dl = t >> 3;
    const int sc = (t & 7) * 8;
#pragma unroll
    for (int i = 0; i < 2; i++) {
        int d = dl + i * 32;
        bf16x8 o;
#pragma unroll
        for (int j = 0; j < 8; j++) o[j] = *(const __bf16*)&Ts[sc + j][d];
        *(bf16x8*)&vt[(size_t)bh * DK * SEQ + (size_t)d * SEQ + s0 + sc] = o;
    }
}

// ---------------- helpers ----------------------------------------------------
static __device__ inline unsigned pack_bf16(float lo, float hi) {
    __hip_bfloat162 t;
    t.x = __float2bfloat16(lo);
    t.y = __float2bfloat16(hi);
    return *reinterpret_cast<unsigned*>(&t);
}

// ---------------- MFMA flash attention, swapped-QK^T in-register softmax ----
// Block = 128 threads = 2 independent waves, same head. Wave0 owns q-rows
// [32j,32j+31] (light), wave1 owns [2048-32j-32,...] (heavy) -> every block
// does exactly 65 subtile-units. No barriers, no K/V LDS staging (per-head
// K/V = 512KB, L2-resident; bh%8 = bid%8 pins each head's blocks to one XCD).
// S^T = mfma_32x32x16(K,Q): lane owns one q-row (lane pair qr/qr+32 split the
// 32 keys); softmax per-lane scalar; cross-half merges via __shfl_xor(...,32).
__global__ __launch_bounds__(128) void attn_mfma(const __hip_bfloat16* __restrict__ qh,
                                                 const __hip_bfloat16* __restrict__ kh,
                                                 const __hip_bfloat16* __restrict__ vt,
                                                 __hip_bfloat16* __restrict__ mergedb) {
    __shared__ __align__(16) __hip_bfloat16 Ob[2][32][72];
    const int tid  = threadIdx.x;
    const int wid  = tid >> 6;
    const int lane = tid & 63;
    const int qr   = lane & 31;     // q-row within wave / K-key row / V-d row
    const int hi   = lane >> 5;
    const int bid  = blockIdx.x;    // 1024 blocks
    const int j    = bid >> 5;      // 0..31
    const int bh   = bid & 31;      // head; bh%8 = XCD
    const int b    = bh >> 4, h = bh & 15;

    const int w    = wid ? (63 - j) : j;   // q-block index 0..63
    const int q0   = w * 32;
    const int nsub = w + 1;                // 32-key subtiles (last = diagonal)

    const __hip_bfloat16* Qb = qh + (size_t)bh * SEQ * DK;
    const __hip_bfloat16* Kb = kh + (size_t)bh * SEQ * DK;
    const __hip_bfloat16* Vb = vt + (size_t)bh * DK * SEQ;   // [64][2048]

    // Q fragments (B-operand): col=lane&31=qrow, k-elem = hi*8+j within chunk i*16
    bf16x8 qf[4];
#pragma unroll
    for (int i = 0; i < 4; i++)
        qf[i] = *(const bf16x8*)&Qb[(size_t)(q0 + qr) * DK + 16 * i + 8 * hi];

    f32x16 acc0 = (f32x16)0.f, acc1 = (f32x16)0.f;   // O^T d-rows 0..31 / 32..63
    float m = -1e30f, lsum = 0.f;                    // finite init: no inf-inf NaN path

    // K fragments, subtile 0 (A-operand): row=lane&31=key, k-elem = hi*8+j
    bf16x8 kf[4];
#pragma unroll
    for (int i = 0; i < 4; i++)
        kf[i] = *(const bf16x8*)&Kb[(size_t)qr * DK + 16 * i + 8 * hi];

    union PW { unsigned w[4]; bf16x8 v; };

    for (int s = 0; s < nsub; s++) {
        const int keybase = s * 32;
        // ---- S^T = K Q : st[r] = S[q0+qr][keybase + (r&3)+8*(r>>2)+4*hi]
        f32x16 st = (f32x16)0.f;
        __builtin_amdgcn_s_setprio(1);
#pragma unroll
        for (int i = 0; i < 4; i++)
            st = __builtin_amdgcn_mfma_f32_32x32x16_bf16(kf[i], qf[i], st, 0, 0, 0);
        __builtin_amdgcn_s_setprio(0);

        // ---- prefetch next K subtile (hides under softmax)
        if (s + 1 < nsub) {
#pragma unroll
            for (int i = 0; i < 4; i++)
                kf[i] = *(const bf16x8*)&Kb[(size_t)(keybase + 32 + qr) * DK + 16 * i + 8 * hi];
        }
        // ---- V fragments for this subtile (A-operand of PV)
        bf16x8 va[2][2];
#pragma unroll
        for (int dt = 0; dt < 2; dt++)
#pragma unroll
            for (int t = 0; t < 2; t++)
                va[dt][t] = *(const bf16x8*)&Vb[(size_t)(dt * 32 + qr) * SEQ + keybase + t * 16 + hi * 8];

        // ---- causal mask (only diagonal subtile: keybase == q0)
        if (s == nsub - 1) {
#pragma unroll
            for (int r = 0; r < 16; r++) {
                int kl = (r & 3) + 8 * (r >> 2) + 4 * hi;
                if (kl > qr) st[r] = -INFINITY;
            }
        }

        // ---- in-register online softmax (one q-row per lane-pair)
        float mx = st[0];
#pragma unroll
        for (int r = 1; r < 16; r++) mx = fmaxf(mx, st[r]);
        mx = fmaxf(mx, __shfl_xor(mx, 32));          // merge key-halves
        float mnew = fmaxf(m, mx);
        float corr = __expf(m - mnew);               // finite - finite always
        m = mnew;
        float ps = 0.f;
#pragma unroll
        for (int r = 0; r < 16; r++) {
            float pv = __expf(st[r] - mnew);         // masked -> exp(-inf)=0
            st[r] = pv;
            ps += pv;
        }
        ps += __shfl_xor(ps, 32);
        lsum = lsum * corr + ps;
#pragma unroll
        for (int r = 0; r < 16; r++) { acc0[r] *= corr; acc1[r] *= corr; }

        // ---- pack P^T into B-operand fragments.
        // Lane needs keys t*16 + hi*8 + j (j=0..7). Own regs hold keys
        // kl=(r&3)+8*(r>>2)+4*hi; partner (lane^32) holds the other halves.
        // c[i] = bf16 pair for key-pairs: hi=0: (0,1)(2,3)(8,9)(10,11)(16..)(..)
        //                                 hi=1: (4,5)(6,7)(12,13)(14,15)(...)
        unsigned c[8];
#pragma unroll
        for (int k2 = 0; k2 < 8; k2++)
            c[k2] = pack_bf16(st[2 * k2], st[2 * k2 + 1]);
        unsigned p0 = __shfl_xor(c[0], 32);
        unsigned p1 = __shfl_xor(c[1], 32);
        unsigned p2 = __shfl_xor(c[2], 32);
        unsigned p3 = __shfl_xor(c[3], 32);
        unsigned p4 = __shfl_xor(c[4], 32);
        unsigned p5 = __shfl_xor(c[5], 32);
        unsigned p6 = __shfl_xor(c[6], 32);
        unsigned p7 = __shfl_xor(c[7], 32);
        PW pa[2];
        // dword0 = keys(hi*8+0,1): hi0 own c0, hi1 partner's c2
        pa[0].w[0] = hi ? p2 : c[0];
        // dword1 = keys(hi*8+2,3): hi0 own c1, hi1 partner's c3
        pa[0].w[1] = hi ? p3 : c[1];
        // dword2 = keys(hi*8+4,5): hi0 partner's c0, hi1 own c2
        pa[0].w[2] = hi ? c[2] : p0;
        // dword3 = keys(hi*8+6,7): hi0 partner's c1, hi1 own c3
        pa[0].w[3] = hi ? c[3] : p1;
        pa[1].w[0] = hi ? p6 : c[4];
        pa[1].w[1] = hi ? p7 : c[5];
        pa[1].w[2] = hi ? c[6] : p4;
        pa[1].w[3] = hi ? c[7] : p5;

        // ---- PV: O^T += V^T P^T
        __builtin_amdgcn_s_setprio(1);
#pragma unroll
        for (int t = 0; t < 2; t++) {
            acc0 = __builtin_amdgcn_mfma_f32_32x32x16_bf16(va[0][t], pa[t].v, acc0, 0, 0, 0);
            acc1 = __builtin_amdgcn_mfma_f32_32x32x16_bf16(va[1][t], pa[t].v, acc1, 0, 0, 0);
        }
        __builtin_amdgcn_s_setprio(0);
    }

    // ---- epilogue: normalize, transpose via per-wave LDS slab, store coalesced
    float invl = 1.0f / lsum;
#pragma unroll
    for (int r = 0; r < 16; r += 2) {
        int d = (r & 3) + 8 * (r >> 2) + 4 * hi;
        *(unsigned*)&Ob[wid][qr][d]      = pack_bf16(acc0[r] * invl, acc0[r + 1] * invl);
        *(unsigned*)&Ob[wid][qr][d + 32] = pack_bf16(acc1[r] * invl, acc1[r + 1] * invl);
    }
    __builtin_amdgcn_wave_barrier();   // wave-internal LDS ordering (compiler waits)
#pragma unroll
    for (int p = 0; p < 4; p++) {
        int row = p * 8 + (lane >> 3);
        int col = (lane & 7) * 8;
        bf16x8 ov = *(const bf16x8*)&Ob[wid][row][col];
        *(bf16x8*)&mergedb[(size_t)(b * SEQ + q0 + row) * DMODEL + h * DK + col] = ov;
    }
}

// ---------------- launch ----------------------------------------------------
extern "C" void kernel_launch(void* const* d_in, const int* in_sizes, int n_in,
                              void* d_out, int out_size, void* d_ws, size_t ws_size,
                              hipStream_t stream) {
    const float* x    = (const float*)d_in[0];
    const float* Wqkv = (const float*)d_in[1];
    const float* Wout = (const float*)d_in[2];
    float* out = (float*)d_out;

    char* w = (char*)d_ws;
    __hip_bfloat16* qkvb   = (__hip_bfloat16*)(w);                       // 24 MB
    __hip_bfloat16* qh     = (__hip_bfloat16*)(w + (24u << 20));         //  8 MB
    __hip_bfloat16* kh     = (__hip_bfloat16*)(w + (32u << 20));         //  8 MB
    __hip_bfloat16* vt     = (__hip_bfloat16*)(w + (40u << 20));         //  8 MB
    __hip_bfloat16* xb     = (__hip_bfloat16*)(w + (48u << 20));         //  8 MB
    __hip_bfloat16* merged = (__hip_bfloat16*)(w + (48u << 20));         //  8 MB (after xb dead)
    __hip_bfloat16* wqkvb  = (__hip_bfloat16*)(w + (56u << 20));         //  6 MB
    __hip_bfloat16* woutb  = (__hip_bfloat16*)(w + (62u << 20));         //  2 MB

    cvt_bf16<<<MTOK * DMODEL / 1024, 256, 0, stream>>>(x, xb, MTOK * DMODEL);
    cvt_bf16<<<QKVN * DMODEL / 1024, 256, 0, stream>>>(Wqkv, wqkvb, QKVN * DMODEL);
    cvt_bf16<<<DMODEL * DMODEL / 1024, 256, 0, stream>>>(Wout, woutb, DMODEL * DMODEL);

    dim3 g1(QKVN / GBN, MTOK / GBM);
    gemm_bf16_nt<1><<<g1, 256, 0, stream>>>(xb, wqkvb, qkvb, MTOK, QKVN, DMODEL);

    rope_qk<<<MTOK * 1024 / 256, 256, 0, stream>>>(qkvb, qh, kh);
    v_trans<<<dim3(SEQ / 64, BH), 256, 0, stream>>>(qkvb, vt);

    attn_mfma<<<1024, 128, 0, stream>>>(qh, kh, vt, merged);

    dim3 g3(DMODEL / GBN, MTOK / GBM);
    gemm_bf16_nt<0><<<g3, 256, 0, stream>>>(merged, woutb, out, MTOK, DMODEL, DMODEL);
}

// Round 8
// 231.786 us; speedup vs baseline: 1.2585x; 1.0064x over previous
//
#include <hip/hip_runtime.h>
#include <hip/hip_bf16.h>
#include <math.h>

#define BATCH   2
#define SEQ     2048
#define DMODEL  1024
#define NHEAD   16
#define DK      64
#define MTOK    (BATCH*SEQ)     // 4096
#define QKVN    (3*DMODEL)      // 3072
#define BH      (BATCH*NHEAD)   // 32

typedef __attribute__((ext_vector_type(8)))  __bf16 bf16x8;
typedef __attribute__((ext_vector_type(4)))  float  f32x4;
typedef __attribute__((ext_vector_type(16))) float  f32x16;

#define GL16(gp, lp) __builtin_amdgcn_global_load_lds( \
    (const __attribute__((address_space(1))) unsigned int*)(gp), \
    (__attribute__((address_space(3))) unsigned int*)(lp), 16, 0, 0)

// ---------------- fp32 -> bf16 convert --------------------------------------
__global__ __launch_bounds__(256) void cvt_bf16(const float* __restrict__ in,
                                                __hip_bfloat16* __restrict__ out, int n) {
    int i = (blockIdx.x * 256 + threadIdx.x) * 4;
    if (i >= n) return;
    float4 v = *(const float4*)(in + i);
    __hip_bfloat162 a, b;
    a.x = __float2bfloat16(v.x); a.y = __float2bfloat16(v.y);
    b.x = __float2bfloat16(v.z); b.y = __float2bfloat16(v.w);
    *(__hip_bfloat162*)(out + i)     = a;
    *(__hip_bfloat162*)(out + i + 2) = b;
}

// ---------------- bf16 MFMA GEMM (NT): C[M,N] = A[M,K] * B[N,K]^T ----------
#define GBM 128
#define GBN 128
#define GBK 32

template<int OUT_BF16>
__global__ __launch_bounds__(256) void gemm_bf16_nt(const __hip_bfloat16* __restrict__ A,
                                                    const __hip_bfloat16* __restrict__ B,
                                                    void* __restrict__ Cv,
                                                    int M, int N, int K) {
    __shared__ __align__(16) __hip_bfloat16 As[GBM][GBK];
    __shared__ __align__(16) __hip_bfloat16 Bs[GBN][GBK];
    const int tid  = threadIdx.x;
    const int wid  = tid >> 6;
    const int lane = tid & 63;
    const int fr   = lane & 15;
    const int fq   = lane >> 4;
    const int wm   = (wid >> 1) * 64;
    const int wn   = (wid & 1) * 64;
    const int m0   = blockIdx.y * GBM;
    const int n0   = blockIdx.x * GBN;

    f32x4 acc[4][4];
#pragma unroll
    for (int m = 0; m < 4; m++)
#pragma unroll
        for (int n = 0; n < 4; n++) acc[m][n] = (f32x4)0.f;

    const __hip_bfloat16* a0 = A + (size_t)(m0 + (tid >> 2)) * K + (tid & 3) * 8;
    const __hip_bfloat16* a1 = a0 + (size_t)64 * K;
    const __hip_bfloat16* b0 = B + (size_t)(n0 + (tid >> 2)) * K + (tid & 3) * 8;
    const __hip_bfloat16* b1 = b0 + (size_t)64 * K;
    __hip_bfloat16* asd0 = &As[0][0] + tid * 8;
    __hip_bfloat16* asd1 = asd0 + 2048;
    __hip_bfloat16* bsd0 = &Bs[0][0] + tid * 8;
    __hip_bfloat16* bsd1 = bsd0 + 2048;

    const __hip_bfloat16* ArP = &As[wm + fr][0] + fq * 8;
    const __hip_bfloat16* BrP = &Bs[wn + fr][0] + fq * 8;

    for (int k0 = 0; k0 < K; k0 += GBK) {
        GL16(a0 + k0, asd0);
        GL16(a1 + k0, asd1);
        GL16(b0 + k0, bsd0);
        GL16(b1 + k0, bsd1);
        __syncthreads();

        bf16x8 af[4], bfv[4];
#pragma unroll
        for (int m = 0; m < 4; m++) af[m]  = *(const bf16x8*)(ArP + m * 512);
#pragma unroll
        for (int n = 0; n < 4; n++) bfv[n] = *(const bf16x8*)(BrP + n * 512);
#pragma unroll
        for (int m = 0; m < 4; m++)
#pragma unroll
            for (int n = 0; n < 4; n++)
                acc[m][n] = __builtin_amdgcn_mfma_f32_16x16x32_bf16(af[m], bfv[n], acc[m][n], 0, 0, 0);
        __syncthreads();
    }

#pragma unroll
    for (int m = 0; m < 4; m++)
#pragma unroll
        for (int n = 0; n < 4; n++)
#pragma unroll
            for (int r = 0; r < 4; r++) {
                size_t row = m0 + wm + m * 16 + fq * 4 + r;
                size_t col = n0 + wn + n * 16 + fr;
                if (OUT_BF16)
                    ((__hip_bfloat16*)Cv)[row * N + col] = __float2bfloat16(acc[m][n][r]);
                else
                    ((float*)Cv)[row * N + col] = acc[m][n][r];
            }
}

// ---------------- RoPE + head-major repack of q,k ---------------------------
// Q pre-scaled by log2e/sqrt(dk) so attention softmax can use native exp2.
__global__ __launch_bounds__(256) void rope_qk(const __hip_bfloat16* __restrict__ qkvb,
                                               __hip_bfloat16* __restrict__ qh,
                                               __hip_bfloat16* __restrict__ kh) {
    int idx  = blockIdx.x * 256 + threadIdx.x;
    int row  = idx >> 10;
    int p    = idx & 1023;
    int half = p >> 9;
    int pp   = p & 511;
    int hh   = pp >> 5;
    int j    = pp & 31;
    int b    = row >> 11, s = row & (SEQ - 1);
    const __hip_bfloat16* src = qkvb + (size_t)row * QKVN + half * DMODEL + hh * DK + 2 * j;
    __hip_bfloat162 xv = *(const __hip_bfloat162*)src;
    float x1 = __bfloat162float(xv.x);
    float x2 = __bfloat162float(xv.y);
    float inv = exp2f(-(float)j * 0.41524101186092030f);
    float ang = (float)s * inv;
    float sn, cs;
    sincosf(ang, &sn, &cs);
    float sc = half ? 1.0f : 0.18033688011112042f;   // 0.125 * log2(e)
    __hip_bfloat162 o;
    o.x = __float2bfloat16((x1 * cs - x2 * sn) * sc);
    o.y = __float2bfloat16((x1 * sn + x2 * cs) * sc);
    __hip_bfloat16* dst = (half ? kh : qh) + ((size_t)(b * NHEAD + hh) * SEQ + s) * DK + 2 * j;
    *(__hip_bfloat162*)dst = o;
}

// ---------------- V transpose (LDS-tiled): vt[bh][d][s] ---------------------
__global__ __launch_bounds__(256) void v_trans(const __hip_bfloat16* __restrict__ qkvb,
                                               __hip_bfloat16* __restrict__ vt) {
    __shared__ __hip_bfloat16 Ts[64][72];
    const int t  = threadIdx.x;
    const int s0 = blockIdx.x * 64;
    const int bh = blockIdx.y;
    const int b  = bh >> 4, h = bh & 15;
    const int sl = t >> 3;
    const int dc = (t & 7) * 8;
#pragma unroll
    for (int i = 0; i < 2; i++) {
        int s = sl + i * 32;
        bf16x8 v = *(const bf16x8*)&qkvb[(size_t)(b * SEQ + s0 + s) * QKVN + 2 * DMODEL + h * DK + dc];
        *(bf16x8*)&Ts[s][dc] = v;
    }
    __syncthreads();
    const int dl = t >> 3;
    const int sc = (t & 7) * 8;
#pragma unroll
    for (int i = 0; i < 2; i++) {
        int d = dl + i * 32;
        bf16x8 o;
#pragma unroll
        for (int j = 0; j < 8; j++) o[j] = *(const __bf16*)&Ts[sc + j][d];
        *(bf16x8*)&vt[(size_t)bh * DK * SEQ + (size_t)d * SEQ + s0 + sc] = o;
    }
}

// ---------------- helpers ----------------------------------------------------
static __device__ inline unsigned pack_bf16(float lo, float hi) {
    __hip_bfloat162 t;
    t.x = __float2bfloat16(lo);
    t.y = __float2bfloat16(hi);
    return *reinterpret_cast<unsigned*>(&t);
}

// ---------------- MFMA flash attention, swapped-QK^T, 1-wave blocks ---------
// Block = 64 threads = 1 wave, owns 32 q-rows (q-block w). Grid 2048 blocks,
// heavy-first (w = 63 - bid/32); bid&31 = bh pins each head's blocks to one
// XCD (K/V L2-resident). Software-pipelined one subtile ahead: loads(s+1) ->
// softmax(s) -> QK-MFMA(s+1) -> pack(s) -> PV(s). Softmax per-lane scalar in
// base-2 (Q pre-scaled by log2e/8); defer-max (THR = 8*log2e); cross-half
// exchanges via __shfl_xor(...,32); l-sum cross-half merge deferred to end.
__global__ __launch_bounds__(64) void attn_mfma(const __hip_bfloat16* __restrict__ qh,
                                                const __hip_bfloat16* __restrict__ kh,
                                                const __hip_bfloat16* __restrict__ vt,
                                                __hip_bfloat16* __restrict__ mergedb) {
    __shared__ __align__(16) __hip_bfloat16 Ob[32][72];
    const int lane = threadIdx.x;
    const int qr   = lane & 31;     // q-row within tile / K-key row / V-d row
    const int hi   = lane >> 5;
    const int bid  = blockIdx.x;    // 2048 blocks
    const int bh   = bid & 31;      // head; bh%8 = XCD
    const int b    = bh >> 4, h = bh & 15;

    const int w    = 63 - (bid >> 5);   // q-block 0..63, heaviest first
    const int q0   = w * 32;
    const int nsub = w + 1;             // 32-key subtiles (last = diagonal)

    const __hip_bfloat16* Qb = qh + (size_t)bh * SEQ * DK;
    const __hip_bfloat16* Kb = kh + (size_t)bh * SEQ * DK;
    const __hip_bfloat16* Vb = vt + (size_t)bh * DK * SEQ;   // [64][2048]

    // Q fragments (B-operand): col=lane&31=qrow, k-elem hi*8+j in chunk i*16
    bf16x8 qf[4];
#pragma unroll
    for (int i = 0; i < 4; i++)
        qf[i] = *(const bf16x8*)&Qb[(size_t)(q0 + qr) * DK + 16 * i + 8 * hi];

    f32x16 acc0 = (f32x16)0.f, acc1 = (f32x16)0.f;   // O^T d-rows 0..31/32..63
    float m = -1e30f, lsum = 0.f;

    union PW { unsigned w[4]; bf16x8 v; };

    // softmax on a score tile (base-2, defer-max)
#define SOFTMAX(ST)                                                            \
    {                                                                          \
        float mx = ST[0];                                                      \
        _Pragma("unroll")                                                      \
        for (int r = 1; r < 16; r++) mx = fmaxf(mx, ST[r]);                    \
        mx = fmaxf(mx, __shfl_xor(mx, 32));                                    \
        if (!__all(mx <= m + 11.5415603f)) {                                   \
            float mnew = fmaxf(m, mx);                                         \
            float corr = exp2f(m - mnew);                                      \
            m = mnew;                                                          \
            lsum *= corr;                                                      \
            _Pragma("unroll")                                                  \
            for (int r = 0; r < 16; r++) { acc0[r] *= corr; acc1[r] *= corr; } \
        }                                                                      \
        float ps = 0.f;                                                        \
        _Pragma("unroll")                                                      \
        for (int r = 0; r < 16; r++) {                                         \
            float pv = exp2f(ST[r] - m);                                       \
            ST[r] = pv;                                                        \
            ps += pv;                                                          \
        }                                                                      \
        lsum += ps;                                                            \
    }

    // pack P^T fragments (4 hi-selected shfls) and run PV
#define PACK_PV(ST, VA)                                                        \
    {                                                                          \
        unsigned c0 = pack_bf16(ST[0],  ST[1]);                                \
        unsigned c1 = pack_bf16(ST[2],  ST[3]);                                \
        unsigned c2 = pack_bf16(ST[4],  ST[5]);                                \
        unsigned c3 = pack_bf16(ST[6],  ST[7]);                                \
        unsigned c4 = pack_bf16(ST[8],  ST[9]);                                \
        unsigned c5 = pack_bf16(ST[10], ST[11]);                               \
        unsigned c6 = pack_bf16(ST[12], ST[13]);                               \
        unsigned c7 = pack_bf16(ST[14], ST[15]);                               \
        unsigned e0 = __shfl_xor(hi ? c0 : c2, 32);                            \
        unsigned e1 = __shfl_xor(hi ? c1 : c3, 32);                            \
        unsigned e2 = __shfl_xor(hi ? c4 : c6, 32);                            \
        unsigned e3 = __shfl_xor(hi ? c5 : c7, 32);                            \
        PW pa0, pa1;                                                           \
        pa0.w[0] = hi ? e0 : c0;                                               \
        pa0.w[1] = hi ? e1 : c1;                                               \
        pa0.w[2] = hi ? c2 : e0;                                               \
        pa0.w[3] = hi ? c3 : e1;                                               \
        pa1.w[0] = hi ? e2 : c4;                                               \
        pa1.w[1] = hi ? e3 : c5;                                               \
        pa1.w[2] = hi ? c6 : e2;                                               \
        pa1.w[3] = hi ? c7 : e3;                                               \
        __builtin_amdgcn_s_setprio(1);                                         \
        acc0 = __builtin_amdgcn_mfma_f32_32x32x16_bf16(VA[0][0], pa0.v, acc0, 0, 0, 0); \
        acc1 = __builtin_amdgcn_mfma_f32_32x32x16_bf16(VA[1][0], pa0.v, acc1, 0, 0, 0); \
        acc0 = __builtin_amdgcn_mfma_f32_32x32x16_bf16(VA[0][1], pa1.v, acc0, 0, 0, 0); \
        acc1 = __builtin_amdgcn_mfma_f32_32x32x16_bf16(VA[1][1], pa1.v, acc1, 0, 0, 0); \
        __builtin_amdgcn_s_setprio(0);                                         \
    }

    // ---- prologue: K(0) + QK(0)
    bf16x8 kf[4];
#pragma unroll
    for (int i = 0; i < 4; i++)
        kf[i] = *(const bf16x8*)&Kb[(size_t)qr * DK + 16 * i + 8 * hi];
    f32x16 st = (f32x16)0.f;
    __builtin_amdgcn_s_setprio(1);
#pragma unroll
    for (int i = 0; i < 4; i++)
        st = __builtin_amdgcn_mfma_f32_32x32x16_bf16(kf[i], qf[i], st, 0, 0, 0);
    __builtin_amdgcn_s_setprio(0);

    // ---- main loop (no mask): finish(s) while QK(s+1) runs
    for (int s = 0; s < nsub - 1; s++) {
        const int keybase = s * 32;
        // issue loads for K(s+1) and V(s) (latency covered by softmax)
        bf16x8 kf2[4];
#pragma unroll
        for (int i = 0; i < 4; i++)
            kf2[i] = *(const bf16x8*)&Kb[(size_t)(keybase + 32 + qr) * DK + 16 * i + 8 * hi];
        bf16x8 va[2][2];
#pragma unroll
        for (int dt = 0; dt < 2; dt++)
#pragma unroll
            for (int t = 0; t < 2; t++)
                va[dt][t] = *(const bf16x8*)&Vb[(size_t)(dt * 32 + qr) * SEQ + keybase + t * 16 + hi * 8];

        SOFTMAX(st);

        // next subtile's QK (MFMA pipe) overlaps pack (VALU)
        f32x16 st2 = (f32x16)0.f;
        __builtin_amdgcn_s_setprio(1);
#pragma unroll
        for (int i = 0; i < 4; i++)
            st2 = __builtin_amdgcn_mfma_f32_32x32x16_bf16(kf2[i], qf[i], st2, 0, 0, 0);
        __builtin_amdgcn_s_setprio(0);

        PACK_PV(st, va);
        st = st2;
    }

    // ---- tail: diagonal subtile with causal mask
    {
        const int keybase = (nsub - 1) * 32;   // == q0
        bf16x8 va[2][2];
#pragma unroll
        for (int dt = 0; dt < 2; dt++)
#pragma unroll
            for (int t = 0; t < 2; t++)
                va[dt][t] = *(const bf16x8*)&Vb[(size_t)(dt * 32 + qr) * SEQ + keybase + t * 16 + hi * 8];
#pragma unroll
        for (int r = 0; r < 16; r++) {
            int kl = (r & 3) + 8 * (r >> 2) + 4 * hi;
            if (kl > qr) st[r] = -INFINITY;
        }
        SOFTMAX(st);
        PACK_PV(st, va);
    }

    // ---- epilogue: merge half-sums, normalize, LDS transpose, store
    lsum += __shfl_xor(lsum, 32);
    float invl = 1.0f / lsum;
#pragma unroll
    for (int r = 0; r < 16; r += 2) {
        int d = (r & 3) + 8 * (r >> 2) + 4 * hi;
        *(unsigned*)&Ob[qr][d]      = pack_bf16(acc0[r] * invl, acc0[r + 1] * invl);
        *(unsigned*)&Ob[qr][d + 32] = pack_bf16(acc1[r] * invl, acc1[r + 1] * invl);
    }
    __builtin_amdgcn_wave_barrier();   // wave-internal LDS ordering
#pragma unroll
    for (int p = 0; p < 4; p++) {
        int row = p * 8 + (lane >> 3);
        int col = (lane & 7) * 8;
        bf16x8 ov = *(const bf16x8*)&Ob[row][col];
        *(bf16x8*)&mergedb[(size_t)(b * SEQ + q0 + row) * DMODEL + h * DK + col] = ov;
    }
#undef SOFTMAX
#undef PACK_PV
}

// ---------------- launch ----------------------------------------------------
extern "C" void kernel_launch(void* const* d_in, const int* in_sizes, int n_in,
                              void* d_out, int out_size, void* d_ws, size_t ws_size,
                              hipStream_t stream) {
    const float* x    = (const float*)d_in[0];
    const float* Wqkv = (const float*)d_in[1];
    const float* Wout = (const float*)d_in[2];
    float* out = (float*)d_out;

    char* w = (char*)d_ws;
    __hip_bfloat16* qkvb   = (__hip_bfloat16*)(w);                       // 24 MB
    __hip_bfloat16* qh     = (__hip_bfloat16*)(w + (24u << 20));         //  8 MB
    __hip_bfloat16* kh     = (__hip_bfloat16*)(w + (32u << 20));         //  8 MB
    __hip_bfloat16* vt     = (__hip_bfloat16*)(w + (40u << 20));         //  8 MB
    __hip_bfloat16* xb     = (__hip_bfloat16*)(w + (48u << 20));         //  8 MB
    __hip_bfloat16* merged = (__hip_bfloat16*)(w + (48u << 20));         //  8 MB (after xb dead)
    __hip_bfloat16* wqkvb  = (__hip_bfloat16*)(w + (56u << 20));         //  6 MB
    __hip_bfloat16* woutb  = (__hip_bfloat16*)(w + (62u << 20));         //  2 MB

    cvt_bf16<<<MTOK * DMODEL / 1024, 256, 0, stream>>>(x, xb, MTOK * DMODEL);
    cvt_bf16<<<QKVN * DMODEL / 1024, 256, 0, stream>>>(Wqkv, wqkvb, QKVN * DMODEL);
    cvt_bf16<<<DMODEL * DMODEL / 1024, 256, 0, stream>>>(Wout, woutb, DMODEL * DMODEL);

    dim3 g1(QKVN / GBN, MTOK / GBM);
    gemm_bf16_nt<1><<<g1, 256, 0, stream>>>(xb, wqkvb, qkvb, MTOK, QKVN, DMODEL);

    rope_qk<<<MTOK * 1024 / 256, 256, 0, stream>>>(qkvb, qh, kh);
    v_trans<<<dim3(SEQ / 64, BH), 256, 0, stream>>>(qkvb, vt);

    attn_mfma<<<2048, 64, 0, stream>>>(qh, kh, vt, merged);

    dim3 g3(DMODEL / GBN, MTOK / GBM);
    gemm_bf16_nt<0><<<g3, 256, 0, stream>>>(merged, woutb, out, MTOK, DMODEL, DMODEL);
}